// Round 1
// baseline (309.073 us; speedup 1.0000x reference)
//
#include <hip/hip_runtime.h>

// Problem constants
#define W 512
#define H 512
#define PLANE (W * H)          // 262144
#define NBATCH 32              // 4*8
#define NPTS (NBATCH * PLANE)  // 8388608 spatial points (per channel)

static constexpr float DT_INV = 100.0f;   // 1/DT, DT=0.01
static constexpr float NU_C   = 0.001f;
// DX = 1.0 -> grad scale 0.5, laplacian scale 1.0

__global__ __launch_bounds__(256) void ns_loss_kernel(
    const float* __restrict__ u_pred,
    const float* __restrict__ u_prev,
    double* __restrict__ ws)
{
    const int tid = blockIdx.x * blockDim.x + threadIdx.x;  // 0 .. NPTS/4-1
    const int xq = tid & 127;          // which group of 4 x's
    const int y  = (tid >> 7) & 511;
    const int b  = tid >> 16;          // batch index 0..31
    const int x4 = xq << 2;

    const float* up0 = u_pred + (size_t)b * (2 * PLANE);
    const float* up1 = up0 + PLANE;
    const float* pr0 = u_prev + (size_t)b * (2 * PLANE);
    const float* pr1 = pr0 + PLANE;

    const int row  = y * W;
    const int rowm = ((y - 1) & 511) * W;
    const int rowp = ((y + 1) & 511) * W;
    const int xm   = (x4 - 1) & 511;   // wraps to 511 when x4==0
    const int xp   = (x4 + 4) & 511;   // wraps to 0 when x4==508

    // channel 0 (u)
    const float4 uc  = *(const float4*)(up0 + row  + x4);
    const float  uL  = up0[row + xm];
    const float  uR  = up0[row + xp];
    const float4 uym = *(const float4*)(up0 + rowm + x4);
    const float4 uyp = *(const float4*)(up0 + rowp + x4);
    // channel 1 (v)
    const float4 vc  = *(const float4*)(up1 + row  + x4);
    const float  vL  = up1[row + xm];
    const float  vR  = up1[row + xp];
    const float4 vym = *(const float4*)(up1 + rowm + x4);
    const float4 vyp = *(const float4*)(up1 + rowp + x4);
    // u_prev centers
    const float4 pu  = *(const float4*)(pr0 + row + x4);
    const float4 pv  = *(const float4*)(pr1 + row + x4);

    const float ua[6] = {uL, uc.x, uc.y, uc.z, uc.w, uR};
    const float va[6] = {vL, vc.x, vc.y, vc.z, vc.w, vR};
    const float uyma[4] = {uym.x, uym.y, uym.z, uym.w};
    const float uypa[4] = {uyp.x, uyp.y, uyp.z, uyp.w};
    const float vyma[4] = {vym.x, vym.y, vym.z, vym.w};
    const float vypa[4] = {vyp.x, vyp.y, vyp.z, vyp.w};
    const float pua[4]  = {pu.x, pu.y, pu.z, pu.w};
    const float pva[4]  = {pv.x, pv.y, pv.z, pv.w};

    float s_pde = 0.0f, s_div = 0.0f;
#pragma unroll
    for (int j = 0; j < 4; ++j) {
        const float u = ua[j + 1];
        const float v = va[j + 1];
        const float u_x = (ua[j + 2] - ua[j]) * 0.5f;
        const float v_x = (va[j + 2] - va[j]) * 0.5f;
        const float u_y = (uypa[j] - uyma[j]) * 0.5f;
        const float v_y = (vypa[j] - vyma[j]) * 0.5f;
        const float lap_u = uypa[j] + uyma[j] + ua[j + 2] + ua[j] - 4.0f * u;
        const float lap_v = vypa[j] + vyma[j] + va[j + 2] + va[j] - 4.0f * v;
        const float rx = (u - pua[j]) * DT_INV + u * u_x + v * u_y - NU_C * lap_u;
        const float ry = (v - pva[j]) * DT_INV + u * v_x + v * v_y - NU_C * lap_v;
        const float dv = u_x + v_y;
        s_pde += rx * rx + ry * ry;
        s_div += dv * dv;
    }

    // wave (64-lane) reduction
#pragma unroll
    for (int off = 32; off > 0; off >>= 1) {
        s_pde += __shfl_down(s_pde, off);
        s_div += __shfl_down(s_div, off);
    }

    __shared__ float sp[4], sd[4];
    const int lane = threadIdx.x & 63;
    const int wv   = threadIdx.x >> 6;
    if (lane == 0) { sp[wv] = s_pde; sd[wv] = s_div; }
    __syncthreads();
    if (threadIdx.x == 0) {
        const float tp = sp[0] + sp[1] + sp[2] + sp[3];
        const float td = sd[0] + sd[1] + sd[2] + sd[3];
        atomicAdd(&ws[0], (double)tp);
        atomicAdd(&ws[1], (double)td);
    }
}

__global__ void ns_finalize_kernel(const double* __restrict__ ws,
                                   float* __restrict__ out)
{
    const double inv = 1.0 / (double)NPTS;
    const double pde = ws[0] * inv;   // (sum rx^2 + sum ry^2) / N
    const double dvl = ws[1] * inv;
    out[0] = (float)(pde + 0.1 * dvl);  // physics_loss
    out[1] = (float)pde;                // pde_loss
    out[2] = (float)dvl;                // div_loss
}

extern "C" void kernel_launch(void* const* d_in, const int* in_sizes, int n_in,
                              void* d_out, int out_size, void* d_ws, size_t ws_size,
                              hipStream_t stream) {
    const float* u_pred = (const float*)d_in[0];
    const float* u_prev = (const float*)d_in[1];
    float* out = (float*)d_out;
    double* ws = (double*)d_ws;

    // ws is poisoned 0xAA before every launch -> zero the accumulators
    hipMemsetAsync(ws, 0, 2 * sizeof(double), stream);

    const int threads = 256;
    const int total_thr = NPTS / 4;           // 2,097,152 threads
    const int blocks = total_thr / threads;   // 8192 blocks

    ns_loss_kernel<<<blocks, threads, 0, stream>>>(u_pred, u_prev, ws);
    ns_finalize_kernel<<<1, 1, 0, stream>>>(ws, out);
}

// Round 2
// 147.860 us; speedup vs baseline: 2.0903x; 2.0903x over previous
//
#include <hip/hip_runtime.h>

#define W 512
#define H 512
#define PLANE (W * H)            // 262144
#define NBATCH 32                // 4*8
#define NPTS (NBATCH * PLANE)    // 8388608 spatial points per channel
#define NBLK 2048                // loss-kernel grid size

static constexpr float DT_INV = 100.0f;   // 1/DT
static constexpr float NU_C   = 0.001f;
// DX = 1.0 -> grad scale 0.5, laplacian scale 1.0

// Each thread: fixed (b, x-quad), walks 4 consecutive rows with a register
// rolling window (row y-1, y, y+1 for both channels). Fully unrolled so the
// compiler can hoist ~26 independent loads -> high MLP.
__global__ __launch_bounds__(256) void ns_loss_v2(
    const float* __restrict__ u_pred,
    const float* __restrict__ u_prev,
    float* __restrict__ partial)
{
    const int tid = blockIdx.x * 256 + threadIdx.x;
    const int xq  = tid & 127;            // x-quad: lanes consecutive -> coalesced
    const int yck = (tid >> 7) & 127;     // 128 chunks of 4 rows
    const int b   = tid >> 14;            // 0..31

    const float* u0 = u_pred + (size_t)b * (2 * PLANE);
    const float* v0 = u0 + PLANE;
    const float* q0 = u_prev + (size_t)b * (2 * PLANE);
    const float* q1 = q0 + PLANE;

    const int x4 = xq << 2;
    const int xm = (x4 - 1) & 511;
    const int xp = (x4 + 4) & 511;
    const int y0 = yck << 2;

    // rolling window: rows y-1 (m) and y (c)
    const int rowm0 = ((y0 - 1) & 511) * W;
    const int row0  = y0 * W;
    float4 um = *(const float4*)(u0 + rowm0 + x4);
    float4 vm = *(const float4*)(v0 + rowm0 + x4);
    float4 uc = *(const float4*)(u0 + row0 + x4);
    float4 vc = *(const float4*)(v0 + row0 + x4);

    float s_pde = 0.0f, s_div = 0.0f;

#pragma unroll
    for (int i = 0; i < 4; ++i) {
        const int y     = y0 + i;            // <= 511, no mask needed
        const int rowc  = y * W;
        const int rowp  = ((y + 1) & 511) * W;

        const float4 up4 = *(const float4*)(u0 + rowp + x4);
        const float4 vp4 = *(const float4*)(v0 + rowp + x4);
        const float  uL  = u0[rowc + xm];
        const float  uR  = u0[rowc + xp];
        const float  vL  = v0[rowc + xm];
        const float  vR  = v0[rowc + xp];
        const float4 pu  = *(const float4*)(q0 + rowc + x4);
        const float4 pv  = *(const float4*)(q1 + rowc + x4);

        const float ua[6]   = {uL, uc.x, uc.y, uc.z, uc.w, uR};
        const float va[6]   = {vL, vc.x, vc.y, vc.z, vc.w, vR};
        const float uyma[4] = {um.x, um.y, um.z, um.w};
        const float uypa[4] = {up4.x, up4.y, up4.z, up4.w};
        const float vyma[4] = {vm.x, vm.y, vm.z, vm.w};
        const float vypa[4] = {vp4.x, vp4.y, vp4.z, vp4.w};
        const float pua[4]  = {pu.x, pu.y, pu.z, pu.w};
        const float pva[4]  = {pv.x, pv.y, pv.z, pv.w};

#pragma unroll
        for (int j = 0; j < 4; ++j) {
            const float u   = ua[j + 1];
            const float v   = va[j + 1];
            const float u_x = (ua[j + 2] - ua[j]) * 0.5f;
            const float v_x = (va[j + 2] - va[j]) * 0.5f;
            const float u_y = (uypa[j] - uyma[j]) * 0.5f;
            const float v_y = (vypa[j] - vyma[j]) * 0.5f;
            const float lap_u = uypa[j] + uyma[j] + ua[j + 2] + ua[j] - 4.0f * u;
            const float lap_v = vypa[j] + vyma[j] + va[j + 2] + va[j] - 4.0f * v;
            const float rx = (u - pua[j]) * DT_INV + u * u_x + v * u_y - NU_C * lap_u;
            const float ry = (v - pva[j]) * DT_INV + u * v_x + v * v_y - NU_C * lap_v;
            const float dv = u_x + v_y;
            s_pde += rx * rx + ry * ry;
            s_div += dv * dv;
        }

        // roll the window
        um = uc; uc = up4;
        vm = vc; vc = vp4;
    }

    // wave (64-lane) reduction
#pragma unroll
    for (int off = 32; off > 0; off >>= 1) {
        s_pde += __shfl_down(s_pde, off);
        s_div += __shfl_down(s_div, off);
    }

    __shared__ float sp[4], sd[4];
    const int lane = threadIdx.x & 63;
    const int wv   = threadIdx.x >> 6;
    if (lane == 0) { sp[wv] = s_pde; sd[wv] = s_div; }
    __syncthreads();
    if (threadIdx.x == 0) {
        // overwrite (poisoned) workspace -> no memset node required
        partial[blockIdx.x]        = sp[0] + sp[1] + sp[2] + sp[3];
        partial[NBLK + blockIdx.x] = sd[0] + sd[1] + sd[2] + sd[3];
    }
}

__global__ __launch_bounds__(256) void ns_reduce(
    const float* __restrict__ partial,
    float* __restrict__ out)
{
    double sp = 0.0, sd = 0.0;
    for (int i = threadIdx.x; i < NBLK; i += 256) {
        sp += (double)partial[i];
        sd += (double)partial[NBLK + i];
    }
#pragma unroll
    for (int off = 32; off > 0; off >>= 1) {
        sp += __shfl_down(sp, off);
        sd += __shfl_down(sd, off);
    }
    __shared__ double ssp[4], ssd[4];
    const int lane = threadIdx.x & 63;
    const int wv   = threadIdx.x >> 6;
    if (lane == 0) { ssp[wv] = sp; ssd[wv] = sd; }
    __syncthreads();
    if (threadIdx.x == 0) {
        const double tp = ssp[0] + ssp[1] + ssp[2] + ssp[3];
        const double td = ssd[0] + ssd[1] + ssd[2] + ssd[3];
        const double inv = 1.0 / (double)NPTS;
        const double pde = tp * inv;
        const double dvl = td * inv;
        out[0] = (float)(pde + 0.1 * dvl);
        out[1] = (float)pde;
        out[2] = (float)dvl;
    }
}

extern "C" void kernel_launch(void* const* d_in, const int* in_sizes, int n_in,
                              void* d_out, int out_size, void* d_ws, size_t ws_size,
                              hipStream_t stream) {
    const float* u_pred = (const float*)d_in[0];
    const float* u_prev = (const float*)d_in[1];
    float* out = (float*)d_out;
    float* partial = (float*)d_ws;   // 2*NBLK floats = 16 KB

    ns_loss_v2<<<NBLK, 256, 0, stream>>>(u_pred, u_prev, partial);
    ns_reduce<<<1, 256, 0, stream>>>(partial, out);
}